// Round 15
// baseline (323.380 us; speedup 1.0000x reference)
//
#include <hip/hip_runtime.h>
#include <hip/hip_bf16.h>

#define M_SAMP 4096
#define D_IN   100
#define HID    256
#define IN_DIM 101
#define NSQ    10000   // 100*100
#define NPAD   10112   // 79*128, padded rows of P
#define SMF    8       // samples per fwd block
#define NFWD   (M_SAMP / SMF)   // 512 fwd blocks
#define NPG    632     // pgen blocks (16 rows each)

typedef __attribute__((ext_vector_type(8))) short short8;
typedef __attribute__((ext_vector_type(4))) float f32x4;

// async global->LDS, 16B/lane; LDS dst wave-uniform (HW adds lane*16)
__device__ __forceinline__ void gload_lds16(const void* g, void* l) {
    __builtin_amdgcn_global_load_lds(
        (const __attribute__((address_space(1))) void*)g,
        (__attribute__((address_space(3))) void*)l, 16, 0, 0);
}

// ============ kernel 1: W1T transpose + P pad-zero (102 blocks) ============
__global__ __launch_bounds__(256) void k_w1t(const float* __restrict__ W1,
                                             float* __restrict__ W1T,
                                             __hip_bfloat16* __restrict__ P) {
    int bid = blockIdx.x, tid = threadIdx.x;
    if (bid < IN_DIM) {
        W1T[bid * HID + tid] = W1[tid * IN_DIM + bid];
    } else {
        short8 zero = {0, 0, 0, 0, 0, 0, 0, 0};
        size_t base = (size_t)NSQ * HID;
        for (int idx = tid; idx < (NPAD - NSQ) * HID / 8; idx += 256)
            *(short8*)&P[base + (size_t)idx * 8] = zero;
    }
}

// == kernel 2: fwd+grad | pgen (R13 code + MEASUREMENT rep loop, idempotent) ==
__global__ __launch_bounds__(256) void k_mid(
        const float* __restrict__ t, const float* __restrict__ X,
        const float* __restrict__ W1, const float* __restrict__ W1T,
        const float* __restrict__ b1, const float* __restrict__ W2,
        const float* __restrict__ b2,
        float* __restrict__ u_out, float* __restrict__ dux,
        float* __restrict__ dut, __hip_bfloat16* __restrict__ S2n,
        __hip_bfloat16* __restrict__ P, int reps) {
    __shared__ __align__(16) char smem[23296];
    int tid = threadIdx.x, bid = blockIdx.x;

    for (int rep = 0; rep < reps; rep++) {
    if (bid < NFWD) {
        float* s_in  = (float*)smem;                  // [8][101] 3232B
        float* c_sh  = (float*)(smem + 3264);         // [8][256] 8192B
        float* us_sh = (float*)(smem + 3264 + 8192);  // [8][256] 8192B
        float* g_sh  = (float*)(smem + 3264 + 16384); // [8][101] 3232B
        int i0 = bid * SMF;

        for (int idx = tid; idx < SMF * IN_DIM; idx += 256) {
            int i = idx / IN_DIM, j = idx % IN_DIM;
            s_in[i * IN_DIM + j] = (j == 0) ? t[i0 + i]
                                            : X[(size_t)(i0 + i) * D_IN + (j - 1)];
        }
        __syncthreads();

        int h = tid;
        float z[SMF];
        float bb = b1[h];
#pragma unroll
        for (int i = 0; i < SMF; i++) z[i] = bb;
        for (int j = 0; j < IN_DIM; j++) {
            float w = W1T[j * HID + h];      // coalesced across lanes
#pragma unroll
            for (int i = 0; i < SMF; i++) z[i] += w * s_in[i * IN_DIM + j];
        }
        float w2 = W2[h];
#pragma unroll
        for (int i = 0; i < SMF; i++) {
            float sz, cz;
            sincosf(z[i], &sz, &cz);
            c_sh[i * HID + h]  = w2 * cz;
            us_sh[i * HID + h] = w2 * sz;
            S2n[(size_t)(i0 + i) * HID + h] = __float2bfloat16(-w2 * sz);
        }
        __syncthreads();

        // u: tree-reduce us_sh rows
        for (int off = 128; off > 0; off >>= 1) {
            if (tid < off) {
#pragma unroll
                for (int i = 0; i < SMF; i++)
                    us_sh[i * HID + tid] += us_sh[i * HID + tid + off];
            }
            __syncthreads();
        }
        if (tid < SMF) u_out[i0 + tid] = us_sh[tid * HID] + b2[0];

        // grad: 2-way h-split; lanes = j -> coalesced W1 row reads.
        int j = tid & 127, grp = tid >> 7;
        bool act = (j < IN_DIM);
        float acc[SMF];
#pragma unroll
        for (int i = 0; i < SMF; i++) acc[i] = 0.f;
        if (act) {
            int hbase = grp * 128;
            for (int h0 = 0; h0 < 128; h0 += 4) {
                float w0 = W1[(size_t)(hbase + h0 + 0) * IN_DIM + j];
                float w1 = W1[(size_t)(hbase + h0 + 1) * IN_DIM + j];
                float w2_ = W1[(size_t)(hbase + h0 + 2) * IN_DIM + j];
                float w3 = W1[(size_t)(hbase + h0 + 3) * IN_DIM + j];
#pragma unroll
                for (int i = 0; i < SMF; i++)
                    acc[i] += c_sh[i * HID + hbase + h0] * w0
                            + c_sh[i * HID + hbase + h0 + 1] * w1
                            + c_sh[i * HID + hbase + h0 + 2] * w2_
                            + c_sh[i * HID + hbase + h0 + 3] * w3;
            }
        }
        if (grp == 1 && act) {
#pragma unroll
            for (int i = 0; i < SMF; i++) g_sh[i * IN_DIM + j] = acc[i];
        }
        __syncthreads();
        if (grp == 0 && act) {
#pragma unroll
            for (int i = 0; i < SMF; i++) acc[i] += g_sh[i * IN_DIM + j];
            if (j == 0) {
                for (int i = 0; i < SMF; i++) dut[i0 + i] = acc[i];
            } else {
                for (int i = 0; i < SMF; i++)
                    dux[(size_t)(i0 + i) * D_IN + (j - 1)] = acc[i];
            }
        }
    } else {
        // -------- pgen: 16 rows per block, W1T rows direct (L2, coalesced) ----
        int n0p = (bid - NFWD) * 16;
        int ksub = tid >> 5, h8 = (tid & 31) * 8;
#pragma unroll
        for (int p = 0; p < 2; p++) {
            int n = n0p + ksub + p * 8;
            if (n < NSQ) {
                int j = n / D_IN, k = n - j * D_IN;
                const float* wj = &W1T[(size_t)(1 + j) * HID + h8];
                const float* wk = &W1T[(size_t)(1 + k) * HID + h8];
                f32x4 aj0 = *(const f32x4*)wj, aj1 = *(const f32x4*)(wj + 4);
                f32x4 bk0 = *(const f32x4*)wk, bk1 = *(const f32x4*)(wk + 4);
                short8 v;
#pragma unroll
                for (int e = 0; e < 4; e++) {
                    __hip_bfloat16 hv = __float2bfloat16(aj0[e] * bk0[e]);
                    v[e] = *reinterpret_cast<short*>(&hv);
                }
#pragma unroll
                for (int e = 0; e < 4; e++) {
                    __hip_bfloat16 hv = __float2bfloat16(aj1[e] * bk1[e]);
                    v[4 + e] = *reinterpret_cast<short*>(&hv);
                }
                *(short8*)&P[(size_t)n * HID + h8] = v;
            }
        }
    }
    __syncthreads();   // rep boundary
    }
}

// == kernel 3: H = S2n @ P^T (R12 winner: BK=64 + XCD order) + rep loop ======
#define BM 128
#define BN 128
#define BK 64
#define NK 4      // 256 / 64
#define NBLK 79   // NPAD / 128

__global__ __launch_bounds__(256) void k_gemm(
        const __hip_bfloat16* __restrict__ A,   // [4096][256] row-major
        const __hip_bfloat16* __restrict__ B,   // [NPAD][256] n-major (=B^T)
        float* __restrict__ C, int reps) {      // [4096][10000]
    __shared__ __hip_bfloat16 As[2][BM * BK];   // 2 x 16 KB
    __shared__ __hip_bfloat16 Bs[2][BM * BK];   // 2 x 16 KB

    int bid = blockIdx.x;
    int xcd = bid & 7, i = bid >> 3;     // 2528 = 8 * 316
    int bn = i >> 2;                     // 0..78  (B-tile shared by 4 adjacent)
    int bm = xcd * 4 + (i & 3);          // XCD x owns bm in [4x, 4x+4)
    int m0 = bm * BM, n0 = bn * BN;
    int tid = threadIdx.x;
    int lane = tid & 63, wave = tid >> 6;
    int wm = wave >> 1, wn = wave & 1;   // 2x2 waves, 64x64 out each

    int srow8 = lane >> 3;               // r & 7
    int scol = ((lane & 7) ^ srow8) * 8; // pre-swizzled source col (bf16 elems)

    auto stage = [&](int buf, int kt) {
        int kc = kt * BK;
#pragma unroll
        for (int q = 0; q < 4; q++) {
            int rb = wave * 32 + q * 8;
            gload_lds16(A + (size_t)(m0 + rb + srow8) * HID + kc + scol,
                        &As[buf][rb * BK]);
            gload_lds16(B + (size_t)(n0 + rb + srow8) * HID + kc + scol,
                        &Bs[buf][rb * BK]);
        }
    };

    for (int rep = 0; rep < reps; rep++) {
        f32x4 acc[4][4];
#pragma unroll
        for (int ii = 0; ii < 4; ii++)
#pragma unroll
            for (int j = 0; j < 4; j++) acc[ii][j] = {0.f, 0.f, 0.f, 0.f};

        stage(0, 0);

        for (int kt = 0; kt < NK; kt++) {
            int cur = kt & 1;
            __syncthreads();             // buf[cur] staged; readers of buf[cur^1] done
            if (kt + 1 < NK) stage(cur ^ 1, kt + 1);

            const char* Ab = (const char*)As[cur];
            const char* Bb = (const char*)Bs[cur];
            int lo = lane & 15;
            int xr = (lane & 7) << 4;    // row-XOR term (r&7 == lane&7)
#pragma unroll
            for (int kk = 0; kk < 2; kk++) {
                int kbs = (kk * 64 + ((lane >> 4) << 4)) ^ xr;
                short8 af[4], bf4[4];
#pragma unroll
                for (int mi = 0; mi < 4; mi++)
                    af[mi] = *(const short8*)(Ab + (wm * 64 + mi * 16 + lo) * 128 + kbs);
#pragma unroll
                for (int ni = 0; ni < 4; ni++)
                    bf4[ni] = *(const short8*)(Bb + (wn * 64 + ni * 16 + lo) * 128 + kbs);
#pragma unroll
                for (int mi = 0; mi < 4; mi++)
#pragma unroll
                    for (int ni = 0; ni < 4; ni++)
                        acc[mi][ni] = __builtin_amdgcn_mfma_f32_16x16x32_bf16(
                            bf4[ni], af[mi], acc[mi][ni], 0, 0, 0);
            }
        }

        int lo = lane & 15, hi4 = (lane >> 4) << 2;
#pragma unroll
        for (int mi = 0; mi < 4; mi++) {
            int mrow = m0 + wm * 64 + mi * 16 + lo;
#pragma unroll
            for (int ni = 0; ni < 4; ni++) {
                int ncol = n0 + wn * 64 + ni * 16 + hi4;
                if (ncol < NSQ)
                    *(f32x4*)&C[(size_t)mrow * NSQ + ncol] = acc[mi][ni];
            }
        }
        __syncthreads();   // LDS reads done before next rep restages
    }
}

extern "C" void kernel_launch(void* const* d_in, const int* in_sizes, int n_in,
                              void* d_out, int out_size, void* d_ws, size_t ws_size,
                              hipStream_t stream) {
    const float* t  = (const float*)d_in[0];
    const float* X  = (const float*)d_in[1];
    const float* W1 = (const float*)d_in[2];
    const float* b1 = (const float*)d_in[3];
    const float* W2 = (const float*)d_in[4];
    const float* b2 = (const float*)d_in[5];

    float* out = (float*)d_out;
    float* u_out = out;                                  // 4096
    float* dux   = out + M_SAMP;                         // 409600
    float* dut   = out + M_SAMP + (size_t)M_SAMP * D_IN; // 4096
    float* H     = dut + M_SAMP;                         // 40,960,000

    char* ws = (char*)d_ws;
    __hip_bfloat16* S2n = (__hip_bfloat16*)ws;                  // 2 MB
    __hip_bfloat16* P   = (__hip_bfloat16*)(ws + 2097152);      // 5.18 MB (padded)
    float* W1T          = (float*)(ws + 2097152 + 5242880);     // 103,424 B

    k_w1t<<<IN_DIM + 1, 256, 0, stream>>>(W1, W1T, P);
    // MEASUREMENT: idempotent rep loops surface both kernels past the fill wall.
    k_mid<<<NFWD + NPG, 256, 0, stream>>>(t, X, W1, W1T, b1, W2, b2,
                                          u_out, dux, dut, S2n, P, 10);
    k_gemm<<<(M_SAMP / BM) * NBLK, 256, 0, stream>>>(S2n, P, H, 3);
}

// Round 16
// 74.727 us; speedup vs baseline: 4.3275x; 4.3275x over previous
//
#include <hip/hip_runtime.h>
#include <hip/hip_bf16.h>

#define M_SAMP 4096
#define D_IN   100
#define HID    256
#define IN_DIM 101
#define NSQ    10000   // 100*100
#define NPAD   10112   // 79*128, padded rows of P
#define SMF    4       // samples per fwd block
#define NFWD   (M_SAMP / SMF)   // 1024 fwd blocks
#define NPG    632     // pgen blocks (16 rows each)

typedef __attribute__((ext_vector_type(8))) short short8;
typedef __attribute__((ext_vector_type(4))) float f32x4;

// async global->LDS, 16B/lane; LDS dst wave-uniform (HW adds lane*16)
__device__ __forceinline__ void gload_lds16(const void* g, void* l) {
    __builtin_amdgcn_global_load_lds(
        (const __attribute__((address_space(1))) void*)g,
        (__attribute__((address_space(3))) void*)l, 16, 0, 0);
}

// ============ kernel 1: W1T transpose + P pad-zero (102 blocks) ============
__global__ __launch_bounds__(256) void k_w1t(const float* __restrict__ W1,
                                             float* __restrict__ W1T,
                                             __hip_bfloat16* __restrict__ P) {
    int bid = blockIdx.x, tid = threadIdx.x;
    if (bid < IN_DIM) {
        W1T[bid * HID + tid] = W1[tid * IN_DIM + bid];
    } else {
        short8 zero = {0, 0, 0, 0, 0, 0, 0, 0};
        size_t base = (size_t)NSQ * HID;
        for (int idx = tid; idx < (NPAD - NSQ) * HID / 8; idx += 256)
            *(short8*)&P[base + (size_t)idx * 8] = zero;
    }
}

// ====== kernel 2: fwd+grad | pgen — SMF=4, native sin/cos, 3 barriers =======
__global__ __launch_bounds__(256) void k_mid(
        const float* __restrict__ t, const float* __restrict__ X,
        const float* __restrict__ W1, const float* __restrict__ W1T,
        const float* __restrict__ b1, const float* __restrict__ W2,
        const float* __restrict__ b2,
        float* __restrict__ u_out, float* __restrict__ dux,
        float* __restrict__ dut, __hip_bfloat16* __restrict__ S2n,
        __hip_bfloat16* __restrict__ P) {
    __shared__ __align__(16) char smem[7488];
    int tid = threadIdx.x, bid = blockIdx.x;

    if (bid < NFWD) {
        float* s_in = (float*)smem;                   // [4][101] 1616B
        float* c_sh = (float*)(smem + 1664);          // [4][256] 4096B
        float* g_sh = (float*)(smem + 1664 + 4096);   // [4][101] 1616B
        float* part = (float*)(smem + 1664 + 4096 + 1632); // [4][4] (within g_sh pad? no: separate)
        // NOTE: g_sh needs 1616B; part placed at +1664+4096+1632 would overlap.
        // Use offset 1664+4096+1616 rounded to 1664+4096+1664 = 7424; part 64B -> 7488 total.
        part = (float*)(smem + 1664 + 4096 + 1664);
        int i0 = bid * SMF;
        int lane = tid & 63, wave = tid >> 6;

        for (int idx = tid; idx < SMF * IN_DIM; idx += 256) {
            int i = idx / IN_DIM, j = idx % IN_DIM;
            s_in[i * IN_DIM + j] = (j == 0) ? t[i0 + i]
                                            : X[(size_t)(i0 + i) * D_IN + (j - 1)];
        }
        __syncthreads();   // barrier 1

        int h = tid;
        float z[SMF];
        float bb = b1[h];
#pragma unroll
        for (int i = 0; i < SMF; i++) z[i] = bb;
        for (int j = 0; j < IN_DIM; j++) {
            float w = W1T[j * HID + h];      // coalesced across lanes
#pragma unroll
            for (int i = 0; i < SMF; i++) z[i] += w * s_in[i * IN_DIM + j];
        }
        float w2 = W2[h];
        float us[SMF];
#pragma unroll
        for (int i = 0; i < SMF; i++) {
            float sz = __sinf(z[i]), cz = __cosf(z[i]);   // native v_sin/v_cos
            c_sh[i * HID + h] = w2 * cz;
            us[i] = w2 * sz;
            S2n[(size_t)(i0 + i) * HID + h] = __float2bfloat16(-w2 * sz);
        }
        // per-wave butterfly reduce us[i] over 64 lanes (no barriers)
#pragma unroll
        for (int i = 0; i < SMF; i++) {
#pragma unroll
            for (int off = 32; off > 0; off >>= 1)
                us[i] += __shfl_xor(us[i], off);
        }
        if (lane == 0) {
#pragma unroll
            for (int i = 0; i < SMF; i++) part[i * 4 + wave] = us[i];
        }
        __syncthreads();   // barrier 2: c_sh + part ready
        if (tid < SMF)
            u_out[i0 + tid] = part[tid * 4] + part[tid * 4 + 1]
                            + part[tid * 4 + 2] + part[tid * 4 + 3] + b2[0];

        // grad: 2-way h-split; lanes = j -> coalesced W1 row reads.
        int j = tid & 127, grp = tid >> 7;
        bool act = (j < IN_DIM);
        float acc[SMF];
#pragma unroll
        for (int i = 0; i < SMF; i++) acc[i] = 0.f;
        if (act) {
            int hbase = grp * 128;
            for (int h0 = 0; h0 < 128; h0 += 4) {
                float w0 = W1[(size_t)(hbase + h0 + 0) * IN_DIM + j];
                float w1 = W1[(size_t)(hbase + h0 + 1) * IN_DIM + j];
                float w2_ = W1[(size_t)(hbase + h0 + 2) * IN_DIM + j];
                float w3 = W1[(size_t)(hbase + h0 + 3) * IN_DIM + j];
#pragma unroll
                for (int i = 0; i < SMF; i++)
                    acc[i] += c_sh[i * HID + hbase + h0] * w0
                            + c_sh[i * HID + hbase + h0 + 1] * w1
                            + c_sh[i * HID + hbase + h0 + 2] * w2_
                            + c_sh[i * HID + hbase + h0 + 3] * w3;
            }
        }
        if (grp == 1 && act) {
#pragma unroll
            for (int i = 0; i < SMF; i++) g_sh[i * IN_DIM + j] = acc[i];
        }
        __syncthreads();   // barrier 3
        if (grp == 0 && act) {
#pragma unroll
            for (int i = 0; i < SMF; i++) acc[i] += g_sh[i * IN_DIM + j];
            if (j == 0) {
                for (int i = 0; i < SMF; i++) dut[i0 + i] = acc[i];
            } else {
                for (int i = 0; i < SMF; i++)
                    dux[(size_t)(i0 + i) * D_IN + (j - 1)] = acc[i];
            }
        }
    } else {
        // -------- pgen: 16 rows per block, W1T rows direct (L2, coalesced) ----
        int n0p = (bid - NFWD) * 16;
        int ksub = tid >> 5, h8 = (tid & 31) * 8;
#pragma unroll
        for (int p = 0; p < 2; p++) {
            int n = n0p + ksub + p * 8;
            if (n < NSQ) {
                int j = n / D_IN, k = n - j * D_IN;
                const float* wj = &W1T[(size_t)(1 + j) * HID + h8];
                const float* wk = &W1T[(size_t)(1 + k) * HID + h8];
                f32x4 aj0 = *(const f32x4*)wj, aj1 = *(const f32x4*)(wj + 4);
                f32x4 bk0 = *(const f32x4*)wk, bk1 = *(const f32x4*)(wk + 4);
                short8 v;
#pragma unroll
                for (int e = 0; e < 4; e++) {
                    __hip_bfloat16 hv = __float2bfloat16(aj0[e] * bk0[e]);
                    v[e] = *reinterpret_cast<short*>(&hv);
                }
#pragma unroll
                for (int e = 0; e < 4; e++) {
                    __hip_bfloat16 hv = __float2bfloat16(aj1[e] * bk1[e]);
                    v[4 + e] = *reinterpret_cast<short*>(&hv);
                }
                *(short8*)&P[(size_t)n * HID + h8] = v;
            }
        }
    }
}

// ====== kernel 3: H = S2n @ P^T (R12 winner: BK=64 + XCD order) =============
#define BM 128
#define BN 128
#define BK 64
#define NK 4      // 256 / 64
#define NBLK 79   // NPAD / 128

__global__ __launch_bounds__(256) void k_gemm(
        const __hip_bfloat16* __restrict__ A,   // [4096][256] row-major
        const __hip_bfloat16* __restrict__ B,   // [NPAD][256] n-major (=B^T)
        float* __restrict__ C) {                // [4096][10000]
    __shared__ __hip_bfloat16 As[2][BM * BK];   // 2 x 16 KB
    __shared__ __hip_bfloat16 Bs[2][BM * BK];   // 2 x 16 KB

    int bid = blockIdx.x;
    int xcd = bid & 7, i = bid >> 3;     // 2528 = 8 * 316
    int bn = i >> 2;                     // 0..78  (B-tile shared by 4 adjacent)
    int bm = xcd * 4 + (i & 3);          // XCD x owns bm in [4x, 4x+4)
    int m0 = bm * BM, n0 = bn * BN;
    int tid = threadIdx.x;
    int lane = tid & 63, wave = tid >> 6;
    int wm = wave >> 1, wn = wave & 1;   // 2x2 waves, 64x64 out each

    int srow8 = lane >> 3;               // r & 7
    int scol = ((lane & 7) ^ srow8) * 8; // pre-swizzled source col (bf16 elems)

    f32x4 acc[4][4];
#pragma unroll
    for (int ii = 0; ii < 4; ii++)
#pragma unroll
        for (int j = 0; j < 4; j++) acc[ii][j] = {0.f, 0.f, 0.f, 0.f};

    auto stage = [&](int buf, int kt) {
        int kc = kt * BK;
#pragma unroll
        for (int q = 0; q < 4; q++) {
            int rb = wave * 32 + q * 8;
            gload_lds16(A + (size_t)(m0 + rb + srow8) * HID + kc + scol,
                        &As[buf][rb * BK]);
            gload_lds16(B + (size_t)(n0 + rb + srow8) * HID + kc + scol,
                        &Bs[buf][rb * BK]);
        }
    };

    stage(0, 0);

    for (int kt = 0; kt < NK; kt++) {
        int cur = kt & 1;
        __syncthreads();                 // buf[cur] staged; readers of buf[cur^1] done
        if (kt + 1 < NK) stage(cur ^ 1, kt + 1);   // prefetch under compute

        const char* Ab = (const char*)As[cur];
        const char* Bb = (const char*)Bs[cur];
        int lo = lane & 15;
        int xr = (lane & 7) << 4;        // row-XOR term (r&7 == lane&7)
#pragma unroll
        for (int kk = 0; kk < 2; kk++) {
            int kbs = (kk * 64 + ((lane >> 4) << 4)) ^ xr;   // swizzled byte-in-row
            short8 af[4], bf4[4];
#pragma unroll
            for (int mi = 0; mi < 4; mi++)
                af[mi] = *(const short8*)(Ab + (wm * 64 + mi * 16 + lo) * 128 + kbs);
#pragma unroll
            for (int ni = 0; ni < 4; ni++)
                bf4[ni] = *(const short8*)(Bb + (wn * 64 + ni * 16 + lo) * 128 + kbs);
            // swapped operands: D = (A.B)^T per-fragment -> lane's f32x4 spans n
#pragma unroll
            for (int mi = 0; mi < 4; mi++)
#pragma unroll
                for (int ni = 0; ni < 4; ni++)
                    acc[mi][ni] = __builtin_amdgcn_mfma_f32_16x16x32_bf16(
                        bf4[ni], af[mi], acc[mi][ni], 0, 0, 0);
        }
    }

    // epilogue: m = lane&15, n = (lane>>4)*4 + reg (consecutive) -> dwordx4
    int lo = lane & 15, hi4 = (lane >> 4) << 2;
#pragma unroll
    for (int mi = 0; mi < 4; mi++) {
        int mrow = m0 + wm * 64 + mi * 16 + lo;
#pragma unroll
        for (int ni = 0; ni < 4; ni++) {
            int ncol = n0 + wn * 64 + ni * 16 + hi4;
            if (ncol < NSQ)
                *(f32x4*)&C[(size_t)mrow * NSQ + ncol] = acc[mi][ni];
        }
    }
}

extern "C" void kernel_launch(void* const* d_in, const int* in_sizes, int n_in,
                              void* d_out, int out_size, void* d_ws, size_t ws_size,
                              hipStream_t stream) {
    const float* t  = (const float*)d_in[0];
    const float* X  = (const float*)d_in[1];
    const float* W1 = (const float*)d_in[2];
    const float* b1 = (const float*)d_in[3];
    const float* W2 = (const float*)d_in[4];
    const float* b2 = (const float*)d_in[5];

    float* out = (float*)d_out;
    float* u_out = out;                                  // 4096
    float* dux   = out + M_SAMP;                         // 409600
    float* dut   = out + M_SAMP + (size_t)M_SAMP * D_IN; // 4096
    float* H     = dut + M_SAMP;                         // 40,960,000

    char* ws = (char*)d_ws;
    __hip_bfloat16* S2n = (__hip_bfloat16*)ws;                  // 2 MB
    __hip_bfloat16* P   = (__hip_bfloat16*)(ws + 2097152);      // 5.18 MB (padded)
    float* W1T          = (float*)(ws + 2097152 + 5242880);     // 103,424 B

    k_w1t<<<IN_DIM + 1, 256, 0, stream>>>(W1, W1T, P);
    k_mid<<<NFWD + NPG, 256, 0, stream>>>(t, X, W1, W1T, b1, W2, b2,
                                          u_out, dux, dut, S2n, P);
    k_gemm<<<(M_SAMP / BM) * NBLK, 256, 0, stream>>>(S2n, P, H);
}